// Round 3
// baseline (1762.750 us; speedup 1.0000x reference)
//
#include <hip/hip_runtime.h>
#include <stdint.h>

// ---------------------------------------------------------------------------
// TransformerBlock fused pipeline for MI355X (gfx950), bf16 MFMA path.
//   B=1024, P=9, D=2700, DFF=512.  M = B*P = 9216 rows.
//   N packed = 8192 (q:0..2699, k:2700..5399, v:5400..8099, pad to 8192)
//   K1 padded 2700->2752 (x @ W), K2 = 1024 exactly ([H1|H2] @ [[WC1],[WC2]])
// Round 5: SPILL FIX. Rounds 3/4 used __launch_bounds__(512,2); the 2nd arg
//   acted as min-BLOCKS/CU (CUDA semantics) -> 4 waves/SIMD -> 128-VGPR cap,
//   but acc[8][4] alone is 128 VGPRs -> the accumulator spilled to scratch.
//   That scratch churn WAS the mystery HBM traffic (FETCH 1.1 GB / WRITE
//   1.3 GB, MfmaUtil 7%). (512,1) -> 2 waves/SIMD -> 256-VGPR budget; ~200
//   needed -> zero spill. Everything else identical to round 4.
// ---------------------------------------------------------------------------

#define MROWS  9216
#define NCOLS  8192
#define KP1    2752
#define KP2    1024
#define DMODEL 2700

typedef __bf16 bf16x8 __attribute__((ext_vector_type(8)));
typedef float  f32x4  __attribute__((ext_vector_type(4)));

__device__ __forceinline__ float b2f(unsigned short u) {
  union { unsigned int u; float f; } v; v.u = ((unsigned int)u) << 16; return v.f;
}
__device__ __forceinline__ unsigned short f2b(float f) {
  union { float f; unsigned int u; } v; v.f = f;
  unsigned int r = v.u + 0x7FFFu + ((v.u >> 16) & 1u);   // RNE
  return (unsigned short)(r >> 16);
}

// async global->LDS, 16B per lane (wave-uniform base + lane*16)
__device__ __forceinline__ void gl2lds16(const void* g, void* l) {
  __builtin_amdgcn_global_load_lds(
      (const __attribute__((address_space(1))) void*)g,
      (__attribute__((address_space(3))) void*)l, 16, 0, 0);
}

// ---------------------------------------------------------------------------
// conversion / packing kernels (unchanged, harness-verified)
// ---------------------------------------------------------------------------

__global__ void cvt_x(const float* __restrict__ src, unsigned short* __restrict__ dst) {
  int idx = blockIdx.x * 256 + threadIdx.x;
  int r = idx / KP1;
  int c = idx - r * KP1;
  float v = (c < DMODEL) ? src[(size_t)r * DMODEL + c] : 0.f;
  dst[idx] = f2b(v);
}

__global__ void cvt_h(const float* __restrict__ H1, const float* __restrict__ H2,
                      unsigned short* __restrict__ dst) {
  int idx = blockIdx.x * 256 + threadIdx.x;
  int r = idx >> 10, c = idx & 1023;
  float v = (c < 512) ? H1[r * 512 + c] : H2[r * 512 + (c - 512)];
  dst[idx] = f2b(v);
}

__global__ void cvt_wqkv(const float* __restrict__ Wq, const float* __restrict__ Wk,
                         const float* __restrict__ Wv, unsigned short* __restrict__ Wt) {
  __shared__ float tile[32][33];
  int k0 = blockIdx.x * 32, n0 = blockIdx.y * 32;
  int tx = threadIdx.x, ty = threadIdx.y;
#pragma unroll
  for (int s = 0; s < 4; s++) {
    int kk = k0 + ty + 8 * s, nn = n0 + tx;
    float v = 0.f;
    if (kk < DMODEL && nn < 3 * DMODEL) {
      int sec = (nn >= 5400) ? 2 : ((nn >= 2700) ? 1 : 0);
      int d = nn - sec * DMODEL;
      const float* W = (sec == 0) ? Wq : ((sec == 1) ? Wk : Wv);
      v = W[(size_t)kk * DMODEL + d];
    }
    tile[ty + 8 * s][tx] = v;
  }
  __syncthreads();
#pragma unroll
  for (int s = 0; s < 4; s++) {
    int nn = n0 + ty + 8 * s, kk = k0 + tx;
    Wt[(size_t)nn * KP1 + kk] = f2b(tile[tx][ty + 8 * s]);
  }
}

__global__ void cvt_wc(const float* __restrict__ C1q, const float* __restrict__ C1k,
                       const float* __restrict__ C1v, const float* __restrict__ C2q,
                       const float* __restrict__ C2k, const float* __restrict__ C2v,
                       unsigned short* __restrict__ Wt) {
  __shared__ float tile[32][33];
  int k0 = blockIdx.x * 32, n0 = blockIdx.y * 32;
  int tx = threadIdx.x, ty = threadIdx.y;
#pragma unroll
  for (int s = 0; s < 4; s++) {
    int kk = k0 + ty + 8 * s, nn = n0 + tx;
    float v = 0.f;
    if (nn < 3 * DMODEL) {
      int sec = (nn >= 5400) ? 2 : ((nn >= 2700) ? 1 : 0);
      int d = nn - sec * DMODEL;
      const float* W;
      int kr = kk;
      if (kk < 512) {
        W = (sec == 0) ? C1q : ((sec == 1) ? C1k : C1v);
      } else {
        W = (sec == 0) ? C2q : ((sec == 1) ? C2k : C2v);
        kr = kk - 512;
      }
      v = W[(size_t)kr * DMODEL + d];
    }
    tile[ty + 8 * s][tx] = v;
  }
  __syncthreads();
#pragma unroll
  for (int s = 0; s < 4; s++) {
    int nn = n0 + ty + 8 * s, kk = k0 + tx;
    Wt[(size_t)nn * KP2 + kk] = f2b(tile[tx][ty + 8 * s]);
  }
}

// ---------------------------------------------------------------------------
// 256x256x(BK=64) 8-phase counted-vmcnt GEMM core (unchanged, verified).
// ---------------------------------------------------------------------------

#define BAR() __builtin_amdgcn_s_barrier()

template<int NT, int KS>
__device__ __forceinline__ void gemm8_core(
    unsigned short (&lds)[2][2][16384],
    const unsigned short* __restrict__ Ab,   // per-thread: + (m0+sr)*KS + skb
    const unsigned short* __restrict__ Bb,   // per-thread: + (n0+sr)*KS + skb
    f32x4 (&acc)[8][4],
    int tid, int wm, int wn, int lm, int lq, int l7)
{
  bf16x8 af[2][4], bfr[2][2];

  auto stage = [&](int buf, int op, int h, int t) {
    const unsigned short* s = (op ? Bb : Ab) + (size_t)(h * 128) * KS + (size_t)(t * 64);
    unsigned short* d = &lds[buf][op][h * 128 * 64 + tid * 8];
    gl2lds16(s, d);
    gl2lds16(s + (size_t)64 * KS, d + 4096);
  };
  auto fragsA = [&](int buf, int MH) {
#pragma unroll
    for (int c = 0; c < 2; c++) {
      const int kx = ((c * 4 + lq) ^ l7) * 8;
#pragma unroll
      for (int t = 0; t < 4; t++)
        af[c][t] = *(const bf16x8*)&lds[buf][0][(wm + MH * 64 + t * 16 + lm) * 64 + kx];
    }
  };
  auto fragsB = [&](int buf, int NH) {
#pragma unroll
    for (int c = 0; c < 2; c++) {
      const int kx = ((c * 4 + lq) ^ l7) * 8;
#pragma unroll
      for (int t = 0; t < 2; t++)
        bfr[c][t] = *(const bf16x8*)&lds[buf][1][(wn + (NH * 2 + t) * 16 + lm) * 64 + kx];
    }
  };
  auto mfmas = [&](int MH, int NH) {
    asm volatile("s_waitcnt lgkmcnt(0)" ::: "memory");
    __builtin_amdgcn_sched_barrier(0);
    __builtin_amdgcn_s_setprio(1);
#pragma unroll
    for (int c = 0; c < 2; c++)
#pragma unroll
      for (int mt = 0; mt < 4; mt++)
#pragma unroll
        for (int nt = 0; nt < 2; nt++)
          acc[MH * 4 + mt][NH * 2 + nt] = __builtin_amdgcn_mfma_f32_16x16x32_bf16(
              af[c][mt], bfr[c][nt], acc[MH * 4 + mt][NH * 2 + nt], 0, 0, 0);
    __builtin_amdgcn_s_setprio(0);
  };

  // prologue: tile 0 -> buf0 (8 loads, no wait; phase 1 of j=0 counts them)
  stage(0, 0, 0, 0); stage(0, 0, 1, 0); stage(0, 1, 0, 0); stage(0, 1, 1, 0);

  const int nfull = NT >> 1;
#pragma unroll 1
  for (int j = 0; j < nfull; ++j) {
    const int t1 = 2 * j + 1, t2 = 2 * j + 2;

    // ---- tile 2j in buf0 ----
    stage(1, 0, 0, t1);                                   // ph1: A.h0 of t1
    asm volatile("s_waitcnt vmcnt(2)" ::: "memory");      // tile 2j landed
    BAR();
    fragsA(0, 0); fragsB(0, 0); mfmas(0, 0);
    BAR();

    fragsB(0, 1); stage(1, 0, 1, t1);                     // ph2: A.h1
    BAR();
    mfmas(0, 1);
    BAR();

    fragsA(0, 1); stage(1, 1, 0, t1);                     // ph3: B.h0
    BAR();
    mfmas(1, 1);
    BAR();

    fragsB(0, 0); stage(1, 1, 1, t1);                     // ph4: B.h1
    BAR();
    mfmas(1, 0);
    BAR();

    // ---- tile 2j+1 in buf1 ----
    if (t2 < NT) {
      stage(0, 0, 0, t2);                                 // ph5: A.h0 of t2
      asm volatile("s_waitcnt vmcnt(2)" ::: "memory");    // tile 2j+1 landed
      BAR();
      fragsA(1, 0); fragsB(1, 0); mfmas(0, 0);
      BAR();

      fragsB(1, 1); stage(0, 0, 1, t2);                   // ph6: A.h1
      BAR();
      mfmas(0, 1);
      BAR();

      fragsA(1, 1); stage(0, 1, 0, t2);                   // ph7: B.h0
      BAR();
      mfmas(1, 1);
      BAR();

      fragsB(1, 0); stage(0, 1, 1, t2);                   // ph8: B.h1
      BAR();
      mfmas(1, 0);
      BAR();
    } else {                                              // even-NT tail
      asm volatile("s_waitcnt vmcnt(0)" ::: "memory");
      BAR();
      fragsA(1, 0); fragsB(1, 0); mfmas(0, 0);
      BAR();
      fragsB(1, 1); mfmas(0, 1);
      BAR();
      fragsA(1, 1); mfmas(1, 1);
      BAR();
      fragsB(1, 0); mfmas(1, 0);
      BAR();
    }
  }
  if (NT & 1) {                                           // odd-NT leftover in buf0
    asm volatile("s_waitcnt vmcnt(0)" ::: "memory");
    BAR();
    fragsA(0, 0); fragsB(0, 0); mfmas(0, 0);
    BAR();
    fragsB(0, 1); mfmas(0, 1);
    BAR();
    fragsA(0, 1); mfmas(1, 1);
    BAR();
    fragsB(0, 0); mfmas(1, 0);
    BAR();
  }
}

// ---------------------------------------------------------------------------
// Full-cacheline C epilogue via LDS transpose (2 passes of 128 rows, fp32).
//   Wave store = 64 x 8 B = 512 contiguous bytes: full 128 B lines.
//   FUSE path reads modulation full-line and multiplies in fp32 (rounded
//   once — numerics identical to the verified round-2 path).
// ---------------------------------------------------------------------------
template<bool FUSE>
__device__ __forceinline__ void epi_store(
    float* L, f32x4 (&acc)[8][4], const float (&bias)[4],
    unsigned short* __restrict__ MQ, int m0, int n0,
    int wave, int lane, int wn, int lm, int lq)
{
#pragma unroll
  for (int pass = 0; pass < 2; ++pass) {
    __syncthreads();
    if ((wave >> 2) == pass) {                 // wm==0 -> pass0, wm==128 -> pass1
#pragma unroll
      for (int mt = 0; mt < 8; mt++) {
#pragma unroll
        for (int nt = 0; nt < 4; nt++) {
          int c = wn + nt * 16 + lm;
#pragma unroll
          for (int i = 0; i < 4; i++) {
            int r = mt * 16 + lq * 4 + i;      // local row within pass
            int b = (c >> 2) ^ (r & 7);        // 16B-block XOR swizzle
            L[r * 256 + b * 4 + (c & 3)] = acc[mt][nt][i] + bias[nt];
          }
        }
      }
    }
    __syncthreads();
#pragma unroll
    for (int it = 0; it < 16; ++it) {
      int rl = it * 8 + wave;
      int bl = lane ^ (rl & 7);                // physical block for logical `lane`
      f32x4 v = *(const f32x4*)&L[rl * 256 + bl * 4];
      size_t go = (size_t)(m0 + pass * 128 + rl) * NCOLS + (n0 + lane * 4);
      ushort4 o;
      if (FUSE) {
        ushort4 md = *(const ushort4*)&MQ[go];
        o.x = f2b(v[0] * b2f(md.x));
        o.y = f2b(v[1] * b2f(md.y));
        o.z = f2b(v[2] * b2f(md.z));
        o.w = f2b(v[3] * b2f(md.w));
      } else {
        o.x = f2b(v[0]); o.y = f2b(v[1]); o.z = f2b(v[2]); o.w = f2b(v[3]);
      }
      *(ushort4*)&MQ[go] = o;
    }
  }
}

// modulation GEMM: MQ = packbf16(Hb @ WCt^T + b1 + b2)
// launch_bounds (512,1): 1 block/CU (128 KiB LDS forces this anyway) ->
// 2 waves/SIMD -> 256-VGPR budget. (512,2) capped at 128 VGPR and spilled acc.
__global__ __launch_bounds__(512, 1) void gemm8_mod(
    const unsigned short* __restrict__ Hb, const unsigned short* __restrict__ WCt,
    unsigned short* __restrict__ MQ,
    const float* __restrict__ b1q, const float* __restrict__ b1k, const float* __restrict__ b1v,
    const float* __restrict__ b2q, const float* __restrict__ b2k, const float* __restrict__ b2v)
{
  __shared__ __attribute__((aligned(16))) unsigned short lds[2][2][16384];
  const int tid = threadIdx.x;
  const int wave = tid >> 6, lane = tid & 63;
  const int wm = (wave >> 2) * 128, wn = (wave & 3) * 64;
  const int lm = lane & 15, lq = lane >> 4, l7 = lane & 7;
  const int wg = blockIdx.x;
  const int swz = (wg & 7) * 144 + (wg >> 3);     // 1152 % 8 == 0: bijective
  const int m0 = (swz >> 5) * 256, n0 = (swz & 31) * 256;
  const int sr = tid >> 3;
  const int skb = ((tid & 7) ^ (sr & 7)) * 8;

  const unsigned short* Ab = Hb  + (size_t)(m0 + sr) * KP2 + skb;
  const unsigned short* Bb = WCt + (size_t)(n0 + sr) * KP2 + skb;

  f32x4 acc[8][4];
#pragma unroll
  for (int i = 0; i < 8; i++)
#pragma unroll
    for (int j = 0; j < 4; j++) acc[i][j] = (f32x4){0.f, 0.f, 0.f, 0.f};

  gemm8_core<16, KP2>(lds, Ab, Bb, acc, tid, wm, wn, lm, lq, l7);

  float bias[4];
#pragma unroll
  for (int nt = 0; nt < 4; nt++) {
    int gc = n0 + wn + nt * 16 + lm;
    float v = 0.f;
    if (gc < 3 * DMODEL) {
      int sec = (gc >= 5400) ? 2 : ((gc >= 2700) ? 1 : 0);
      int d = gc - sec * DMODEL;
      const float* u1 = (sec == 0) ? b1q : ((sec == 1) ? b1k : b1v);
      const float* u2 = (sec == 0) ? b2q : ((sec == 1) ? b2k : b2v);
      v = u1[d] + u2[d];
    }
    bias[nt] = v;
  }
  epi_store<false>((float*)&lds[0][0][0], acc, bias, MQ, m0, n0, wave, lane, wn, lm, lq);
}

// main GEMM + fuse: MQ = packbf16((Xb @ Wt^T + b) * MQ)
__global__ __launch_bounds__(512, 1) void gemm8_main(
    const unsigned short* __restrict__ Xb, const unsigned short* __restrict__ Wt,
    unsigned short* MQ,
    const float* __restrict__ bq_, const float* __restrict__ bk_, const float* __restrict__ bv_)
{
  __shared__ __attribute__((aligned(16))) unsigned short lds[2][2][16384];
  const int tid = threadIdx.x;
  const int wave = tid >> 6, lane = tid & 63;
  const int wm = (wave >> 2) * 128, wn = (wave & 3) * 64;
  const int lm = lane & 15, lq = lane >> 4, l7 = lane & 7;
  const int wg = blockIdx.x;
  const int swz = (wg & 7) * 144 + (wg >> 3);
  const int m0 = (swz >> 5) * 256, n0 = (swz & 31) * 256;
  const int sr = tid >> 3;
  const int skb = ((tid & 7) ^ (sr & 7)) * 8;

  const unsigned short* Ab = Xb + (size_t)(m0 + sr) * KP1 + skb;
  const unsigned short* Bb = Wt + (size_t)(n0 + sr) * KP1 + skb;

  f32x4 acc[8][4];
#pragma unroll
  for (int i = 0; i < 8; i++)
#pragma unroll
    for (int j = 0; j < 4; j++) acc[i][j] = (f32x4){0.f, 0.f, 0.f, 0.f};

  gemm8_core<43, KP1>(lds, Ab, Bb, acc, tid, wm, wn, lm, lq, l7);

  float bias[4];
#pragma unroll
  for (int nt = 0; nt < 4; nt++) {
    int gc = n0 + wn + nt * 16 + lm;
    float v = 0.f;
    if (gc < 3 * DMODEL) {
      int sec = (gc >= 5400) ? 2 : ((gc >= 2700) ? 1 : 0);
      int d = gc - sec * DMODEL;
      const float* bm = (sec == 0) ? bq_ : ((sec == 1) ? bk_ : bv_);
      v = bm[d];
    }
    bias[nt] = v;
  }
  epi_store<true>((float*)&lds[0][0][0], acc, bias, MQ, m0, n0, wave, lane, wn, lm, lq);
}

// ---------------------------------------------------------------------------
// Fused attention (9x9) + softmax + residual + LayerNorm (unchanged, verified)
// ---------------------------------------------------------------------------
__global__ __launch_bounds__(256, 2) void attn_ln(
    const unsigned short* __restrict__ qkv,  // [9216][8192] bf16 (q|k|v packed)
    const float* __restrict__ x,             // [9216][2700] fp32
    const float* __restrict__ gamma, const float* __restrict__ beta,
    float* __restrict__ out)                 // [9216][2700] fp32
{
  __shared__ float part[4][81];
  __shared__ float sc[81];
  __shared__ float redS[4][9], redQ[4][9];
  __shared__ float muL[9], rsL[9];

  const int b = blockIdx.x;
  const int tid = threadIdx.x, wave = tid >> 6, lane = tid & 63;
  const unsigned short* qb = qkv + (size_t)b * 9 * NCOLS;

  // ---- phase 1: scores S[i][j] = q_i . k_j via 16x16x32 MFMA, K-split ----
  {
    const int l15 = lane & 15, lq8 = (lane >> 4) * 8;
    const int rA = (l15 < 9) ? l15 : 8;                 // clamp: rows 9..15 junk
    const unsigned short* qrow = qb + (size_t)rA * NCOLS;          // 16B aligned
    const unsigned short* krow = qb + (size_t)rA * NCOLS + DMODEL; // 8B aligned
    f32x4 accS = (f32x4){0.f, 0.f, 0.f, 0.f};
    for (int s = wave; s < 85; s += 4) {                // 85 = ceil(2700/32)
      int k0 = s * 32 + lq8;
      union { uint2 u[2]; unsigned int w[4]; bf16x8 v; } au, bu;
      au.u[0] = *(const uint2*)(qrow + k0);
      au.u[1] = *(const uint2*)(qrow + k0 + 4);
      bu.u[0] = *(const uint2*)(krow + k0);
      bu.u[1] = *(const uint2*)(krow + k0 + 4);
      if (s == 84) {                                    // mask k >= 2700
#pragma unroll
        for (int wd = 0; wd < 4; wd++)
          if (k0 + 2 * wd >= DMODEL) { au.w[wd] = 0u; bu.w[wd] = 0u; }
      }
      accS = __builtin_amdgcn_mfma_f32_16x16x32_bf16(au.v, bu.v, accS, 0, 0, 0);
    }
#pragma unroll
    for (int i = 0; i < 4; i++) {
      int row = (lane >> 4) * 4 + i, col = l15;
      if (row < 9 && col < 9) part[wave][row * 9 + col] = accS[i];
    }
  }
  __syncthreads();

  if (tid < 81)
    sc[tid] = (part[0][tid] + part[1][tid] + part[2][tid] + part[3][tid])
              * 0.019245008972987526f;                  // 1/sqrt(2700)
  __syncthreads();

  // ---- phase 2: softmax per row (threads 0..8) ----
  if (tid < 9) {
    float mx = -1e30f;
#pragma unroll
    for (int j = 0; j < 9; j++) mx = fmaxf(mx, sc[tid * 9 + j]);
    float e[9], sum = 0.f;
#pragma unroll
    for (int j = 0; j < 9; j++) { e[j] = __expf(sc[tid * 9 + j] - mx); sum += e[j]; }
    float inv = 1.f / sum;
#pragma unroll
    for (int j = 0; j < 9; j++) sc[tid * 9 + j] = e[j] * inv;
  }
  __syncthreads();

  // ---- phase 3: t = x + A.V for all 9 rows, per float4 column-chunk ----
  float sum[9], sq[9];
#pragma unroll
  for (int i = 0; i < 9; i++) { sum[i] = 0.f; sq[i] = 0.f; }
  unsigned int pv[9][3][2];
#pragma unroll
  for (int c = 0; c < 3; c++) {
    int e = tid + c * 256;
    if (e < 675) {                                      // 675 = 2700/4
      float4 t4[9];
#pragma unroll
      for (int i = 0; i < 9; i++)
        t4[i] = ((const float4*)(x + (size_t)(b * 9 + i) * DMODEL))[e];
#pragma unroll
      for (int j = 0; j < 9; j++) {
        ushort4 vv = ((const ushort4*)(qb + (size_t)j * NCOLS + 5400))[e];
        float v0 = b2f(vv.x), v1 = b2f(vv.y), v2 = b2f(vv.z), v3 = b2f(vv.w);
#pragma unroll
        for (int i = 0; i < 9; i++) {
          float p = sc[i * 9 + j];
          t4[i].x += p * v0; t4[i].y += p * v1;
          t4[i].z += p * v2; t4[i].w += p * v3;
        }
      }
#pragma unroll
      for (int i = 0; i < 9; i++) {
        sum[i] += t4[i].x + t4[i].y + t4[i].z + t4[i].w;
        sq[i]  += t4[i].x * t4[i].x + t4[i].y * t4[i].y
                + t4[i].z * t4[i].z + t4[i].w * t4[i].w;
        pv[i][c][0] = (unsigned int)f2b(t4[i].x) | ((unsigned int)f2b(t4[i].y) << 16);
        pv[i][c][1] = (unsigned int)f2b(t4[i].z) | ((unsigned int)f2b(t4[i].w) << 16);
      }
    }
  }

  // ---- phase 4: block reduction for all 9 rows ----
#pragma unroll
  for (int i = 0; i < 9; i++) {
    float s = sum[i], q = sq[i];
#pragma unroll
    for (int off = 32; off > 0; off >>= 1) {
      s += __shfl_down(s, off, 64);
      q += __shfl_down(q, off, 64);
    }
    if (lane == 0) { redS[wave][i] = s; redQ[wave][i] = q; }
  }
  __syncthreads();
  if (tid < 9) {
    float ts = redS[0][tid] + redS[1][tid] + redS[2][tid] + redS[3][tid];
    float tq = redQ[0][tid] + redQ[1][tid] + redQ[2][tid] + redQ[3][tid];
    float mu = ts * (1.f / 2700.f);
    muL[tid] = mu;
    rsL[tid] = rsqrtf(tq * (1.f / 2700.f) - mu * mu + 1e-5f);
  }
  __syncthreads();

  // ---- phase 5: LN write, float4 ----
#pragma unroll
  for (int c = 0; c < 3; c++) {
    int e = tid + c * 256;
    if (e < 675) {
      float4 g = ((const float4*)gamma)[e];
      float4 bb = ((const float4*)beta)[e];
#pragma unroll
      for (int i = 0; i < 9; i++) {
        float m = muL[i], r = rsL[i];
        float t0 = b2f((unsigned short)(pv[i][c][0] & 0xFFFF));
        float t1 = b2f((unsigned short)(pv[i][c][0] >> 16));
        float t2 = b2f((unsigned short)(pv[i][c][1] & 0xFFFF));
        float t3 = b2f((unsigned short)(pv[i][c][1] >> 16));
        float4 o;
        o.x = (t0 - m) * r * g.x + bb.x;
        o.y = (t1 - m) * r * g.y + bb.y;
        o.z = (t2 - m) * r * g.z + bb.z;
        o.w = (t3 - m) * r * g.w + bb.w;
        ((float4*)(out + (size_t)(b * 9 + i) * DMODEL))[e] = o;
      }
    }
  }
}

// ---------------------------------------------------------------------------
extern "C" void kernel_launch(void* const* d_in, const int* in_sizes, int n_in,
                              void* d_out, int out_size, void* d_ws, size_t ws_size,
                              hipStream_t stream) {
  const float* state = (const float*)d_in[0];
  const float* H1    = (const float*)d_in[1];
  const float* H2    = (const float*)d_in[2];
  const float* Wq    = (const float*)d_in[3];
  const float* bq    = (const float*)d_in[4];
  const float* Wk    = (const float*)d_in[5];
  const float* bk    = (const float*)d_in[6];
  const float* Wv    = (const float*)d_in[7];
  const float* bv    = (const float*)d_in[8];
  const float* WC1q  = (const float*)d_in[9];
  const float* bC1q  = (const float*)d_in[10];
  const float* WC1k  = (const float*)d_in[11];
  const float* bC1k  = (const float*)d_in[12];
  const float* WC1v  = (const float*)d_in[13];
  const float* bC1v  = (const float*)d_in[14];
  const float* WC2q  = (const float*)d_in[15];
  const float* bC2q  = (const float*)d_in[16];
  const float* WC2k  = (const float*)d_in[17];
  const float* bC2k  = (const float*)d_in[18];
  const float* WC2v  = (const float*)d_in[19];
  const float* bC2v  = (const float*)d_in[20];
  const float* gamma = (const float*)d_in[21];
  const float* beta  = (const float*)d_in[22];
  float* out = (float*)d_out;

  // workspace layout (256B aligned), total 282,460,160 B
  char* ws = (char*)d_ws;
  unsigned short* Xb  = (unsigned short*)(ws + 0);            // 9216*2752*2
  unsigned short* Wt  = (unsigned short*)(ws + 50724864);     // 8192*2752*2
  unsigned short* Hb  = (unsigned short*)(ws + 95813632);     // 9216*1024*2
  unsigned short* WCt = (unsigned short*)(ws + 114688000);    // 8192*1024*2
  unsigned short* MQ  = (unsigned short*)(ws + 131465216);    // 9216*8192*2

  // 1) convert / pack
  cvt_h<<<dim3(MROWS * KP2 / 256), dim3(256), 0, stream>>>(H1, H2, Hb);
  cvt_wc<<<dim3(KP2 / 32, NCOLS / 32), dim3(32, 8), 0, stream>>>(WC1q, WC1k, WC1v,
                                                                 WC2q, WC2k, WC2v, WCt);
  cvt_x<<<dim3(MROWS * KP1 / 256), dim3(256), 0, stream>>>(state, Xb);
  cvt_wqkv<<<dim3(KP1 / 32, NCOLS / 32), dim3(32, 8), 0, stream>>>(Wq, Wk, Wv, Wt);

  // 2) modulation GEMM (256x256 8-phase): MQ = bf16(Hb@WCt^T + bmod)
  gemm8_mod<<<dim3(MROWS / 256 * NCOLS / 256), dim3(512), 0, stream>>>(
      Hb, WCt, MQ, bC1q, bC1k, bC1v, bC2q, bC2k, bC2v);

  // 3) main GEMM + fuse (256x256 8-phase): MQ = bf16((Xb@Wt^T + b) * MQ)
  gemm8_main<<<dim3(MROWS / 256 * NCOLS / 256), dim3(512), 0, stream>>>(
      Xb, Wt, MQ, bq, bk, bv);

  // 4) attention + softmax + residual + layernorm
  attn_ln<<<dim3(1024), dim3(256), 0, stream>>>(MQ, state, gamma, beta, out);
}

// Round 4
// 1079.291 us; speedup vs baseline: 1.6332x; 1.6332x over previous
//
#include <hip/hip_runtime.h>
#include <stdint.h>

// ---------------------------------------------------------------------------
// TransformerBlock fused pipeline for MI355X (gfx950), bf16 MFMA path.
//   B=1024, P=9, D=2700, DFF=512.  M = B*P = 9216 rows.
//   N packed = 8192 (q:0..2699, k:2700..5399, v:5400..8099, pad to 8192)
//   K1 padded 2700->2752 (x @ W), K2 = 1024 exactly ([H1|H2] @ [[WC1],[WC2]])
// Round 6: REVERT GEMM to the verified round-2 gemm_fused (723 us, MfmaUtil
//   35%, clean traffic). The 256^2/8-wave experiments (rounds 3-5) all hit an
//   undiagnosed 9x write-amp + MfmaUtil 7% pathology; three failed predictions
//   -> bank the verified baseline. This round attacks the ~270 us of slack in
//   the side kernels instead:
//   - cvt_x / cvt_h: scalar 1-elem/thread -> vectorized 8 elems/thread
//     (float4 x2 reads, uint4 store).  [G13: scalar bf16 ~2-2.5x slow]
//   - cvt_wqkv / cvt_wc: 32x32 tiles wrote 64 B half-lines (partial-line RMW
//     at HBM) -> 64x64 tiles, 256 B reads / 128 B full-line writes.
//   gemm_fused and attn_ln are byte-identical to the 1109-us verified kernel.
// ---------------------------------------------------------------------------

#define MROWS  9216
#define NCOLS  8192
#define KP1    2752
#define KP2    1024
#define DMODEL 2700

typedef __bf16 bf16x8 __attribute__((ext_vector_type(8)));
typedef float  f32x4  __attribute__((ext_vector_type(4)));

__device__ __forceinline__ float b2f(unsigned short u) {
  union { unsigned int u; float f; } v; v.u = ((unsigned int)u) << 16; return v.f;
}
__device__ __forceinline__ unsigned short f2b(float f) {
  union { float f; unsigned int u; } v; v.f = f;
  unsigned int r = v.u + 0x7FFFu + ((v.u >> 16) & 1u);   // RNE
  return (unsigned short)(r >> 16);
}

// async global->LDS, 16B per lane (wave-uniform base + lane*16)
__device__ __forceinline__ void gl2lds16(const void* g, void* l) {
  __builtin_amdgcn_global_load_lds(
      (const __attribute__((address_space(1))) void*)g,
      (__attribute__((address_space(3))) void*)l, 16, 0, 0);
}

// ---------------------------------------------------------------------------
// conversion / packing kernels — vectorized / full-cacheline versions
// ---------------------------------------------------------------------------

// state fp32 -> Xb bf16 [9216][2752], 8 elems/thread. 2752/8=344.
__global__ void cvt_x(const float* __restrict__ src, unsigned short* __restrict__ dst) {
  int t = blockIdx.x * 256 + threadIdx.x;          // grid: 9216*344/256 = 12384
  int r = t / 344;
  int c8 = (t - r * 344) * 8;
  const float* row = src + (size_t)r * DMODEL;
  unsigned int w[4];
  if (c8 + 8 <= DMODEL) {                          // fast path, 16B-aligned
    float4 a = *(const float4*)(row + c8);
    float4 b = *(const float4*)(row + c8 + 4);
    w[0] = (unsigned int)f2b(a.x) | ((unsigned int)f2b(a.y) << 16);
    w[1] = (unsigned int)f2b(a.z) | ((unsigned int)f2b(a.w) << 16);
    w[2] = (unsigned int)f2b(b.x) | ((unsigned int)f2b(b.y) << 16);
    w[3] = (unsigned int)f2b(b.z) | ((unsigned int)f2b(b.w) << 16);
  } else {                                         // boundary/pad threads
#pragma unroll
    for (int h = 0; h < 4; h++) {
      int c0 = c8 + 2 * h, c1 = c8 + 2 * h + 1;
      unsigned int lo = (c0 < DMODEL) ? f2b(row[c0]) : 0u;
      unsigned int hi = (c1 < DMODEL) ? f2b(row[c1]) : 0u;
      w[h] = lo | (hi << 16);
    }
  }
  *(uint4*)(dst + (size_t)t * 8) = make_uint4(w[0], w[1], w[2], w[3]);
}

// [H1|H2] fp32 -> Hb bf16 [9216][1024], 8 elems/thread.
__global__ void cvt_h(const float* __restrict__ H1, const float* __restrict__ H2,
                      unsigned short* __restrict__ dst) {
  int t = blockIdx.x * 256 + threadIdx.x;          // grid: 9216*128/256 = 4608
  int r = t >> 7, c8 = (t & 127) * 8;
  const float* row = (c8 < 512) ? (H1 + (size_t)r * 512 + c8)
                                : (H2 + (size_t)r * 512 + (c8 - 512));
  float4 a = *(const float4*)(row);
  float4 b = *(const float4*)(row + 4);
  unsigned int w0 = (unsigned int)f2b(a.x) | ((unsigned int)f2b(a.y) << 16);
  unsigned int w1 = (unsigned int)f2b(a.z) | ((unsigned int)f2b(a.w) << 16);
  unsigned int w2 = (unsigned int)f2b(b.x) | ((unsigned int)f2b(b.y) << 16);
  unsigned int w3 = (unsigned int)f2b(b.z) | ((unsigned int)f2b(b.w) << 16);
  *(uint4*)(dst + (size_t)t * 8) = make_uint4(w0, w1, w2, w3);
}

// Wq/Wk/Wv (2700x2700, row-major k,d) -> Wt[n][k] bf16 [8192][2752].
// 64x64 transpose tile: reads 256 B contiguous, writes 128 B full lines.
__global__ void cvt_wqkv(const float* __restrict__ Wq, const float* __restrict__ Wk,
                         const float* __restrict__ Wv, unsigned short* __restrict__ Wt) {
  __shared__ float tile[64][65];
  const int k0 = blockIdx.x * 64;                  // 43 blocks (2752)
  const int n0 = blockIdx.y * 64;                  // 128 blocks (8192)
  const int tx = threadIdx.x & 63, tg = threadIdx.x >> 6;
  const int nn_r = n0 + tx;
  int sec = (nn_r >= 5400) ? 2 : ((nn_r >= 2700) ? 1 : 0);
  int d = nn_r - sec * DMODEL;
  const float* W = (sec == 0) ? Wq : ((sec == 1) ? Wk : Wv);
  bool cvalid = (nn_r < 3 * DMODEL);
#pragma unroll
  for (int rr = 0; rr < 16; rr++) {
    int kk = k0 + tg * 16 + rr;
    float v = 0.f;
    if (kk < DMODEL && cvalid) v = W[(size_t)kk * DMODEL + d];
    tile[tg * 16 + rr][tx] = v;
  }
  __syncthreads();
#pragma unroll
  for (int rr = 0; rr < 16; rr++) {
    int nn = n0 + tg * 16 + rr;
    Wt[(size_t)nn * KP1 + k0 + tx] = f2b(tile[tx][tg * 16 + rr]);
  }
}

// WC1x/WC2x (512xD each) -> WCt[n][k] bf16 [8192][1024]; k<512 from C1, else C2.
__global__ void cvt_wc(const float* __restrict__ C1q, const float* __restrict__ C1k,
                       const float* __restrict__ C1v, const float* __restrict__ C2q,
                       const float* __restrict__ C2k, const float* __restrict__ C2v,
                       unsigned short* __restrict__ Wt) {
  __shared__ float tile[64][65];
  const int k0 = blockIdx.x * 64;                  // 16 blocks (1024)
  const int n0 = blockIdx.y * 64;                  // 128 blocks (8192)
  const int tx = threadIdx.x & 63, tg = threadIdx.x >> 6;
  const int nn_r = n0 + tx;
  int sec = (nn_r >= 5400) ? 2 : ((nn_r >= 2700) ? 1 : 0);
  int d = nn_r - sec * DMODEL;
  bool cvalid = (nn_r < 3 * DMODEL);
  const float* W1 = (sec == 0) ? C1q : ((sec == 1) ? C1k : C1v);
  const float* W2 = (sec == 0) ? C2q : ((sec == 1) ? C2k : C2v);
#pragma unroll
  for (int rr = 0; rr < 16; rr++) {
    int kk = k0 + tg * 16 + rr;
    const float* W = (kk < 512) ? W1 : W2;
    int kr = (kk < 512) ? kk : (kk - 512);
    float v = cvalid ? W[(size_t)kr * DMODEL + d] : 0.f;
    tile[tg * 16 + rr][tx] = v;
  }
  __syncthreads();
#pragma unroll
  for (int rr = 0; rr < 16; rr++) {
    int nn = n0 + tg * 16 + rr;
    Wt[(size_t)nn * KP2 + k0 + tx] = f2b(tile[tx][tg * 16 + rr]);
  }
}

// ---------------------------------------------------------------------------
// Fused double GEMM (VERIFIED round-2 kernel, byte-identical):
//   phase A: mod  = Hb(9216x1024) @ WCt^T(8192x1024)   -> saved packed bf16
//   phase B: main = Xb(9216x2752) @ Wt^T(8192x2752)
//   epilogue: MQ = (main + bmain) * (mod + bmod)  (bf16)
// 128x128 tile, BK=64, 4 waves (2x2) each 64x64 via 4x4 of 16x16x32 MFMA.
// global_load_lds width=16 with XOR swizzle on 16B blocks.
// ---------------------------------------------------------------------------
__global__ __launch_bounds__(256, 2) void gemm_fused(
    const unsigned short* __restrict__ Xb,
    const unsigned short* __restrict__ Wt,
    const unsigned short* __restrict__ Hb,
    const unsigned short* __restrict__ WCt,
    unsigned short* __restrict__ MQ,
    const float* __restrict__ bq_, const float* __restrict__ bk_, const float* __restrict__ bv_,
    const float* __restrict__ b1q, const float* __restrict__ b1k, const float* __restrict__ b1v,
    const float* __restrict__ b2q, const float* __restrict__ b2k, const float* __restrict__ b2v)
{
  __shared__ __align__(16) unsigned short As[128 * 64];
  __shared__ __align__(16) unsigned short Bs[128 * 64];
  const int tid = threadIdx.x;
  const int wave = tid >> 6, lane = tid & 63;
  const int m0 = blockIdx.y * 128, n0 = blockIdx.x * 128;
  const int wm = (wave >> 1) * 64, wn = (wave & 1) * 64;
  const int lm = lane & 15, lq = lane >> 4, l7 = lane & 7;

  // staging geometry: phys block p = r*256+tid holds logical row p>>3,
  // k-block (p&7)^(row&7); offsets in ushort elements.
  int prow[4], pcl[4];
  unsigned int ldsoff[4];
#pragma unroll
  for (int r = 0; r < 4; r++) {
    int p = r * 256 + tid;
    prow[r] = p >> 3;
    pcl[r] = ((p & 7) ^ (prow[r] & 7)) * 8;
    ldsoff[r] = (unsigned int)p * 8;
  }

  f32x4 acc[4][4];
#pragma unroll
  for (int i = 0; i < 4; i++)
#pragma unroll
    for (int j = 0; j < 4; j++) acc[i][j] = (f32x4){0.f, 0.f, 0.f, 0.f};

  // ---------------- phase A: modulation GEMM, K = 1024 ----------------
  for (int k0 = 0; k0 < KP2; k0 += 64) {
#pragma unroll
    for (int r = 0; r < 4; r++) {
      gl2lds16(Hb + (size_t)(m0 + prow[r]) * KP2 + pcl[r] + k0, As + ldsoff[r]);
      gl2lds16(WCt + (size_t)(n0 + prow[r]) * KP2 + pcl[r] + k0, Bs + ldsoff[r]);
    }
    __syncthreads();
#pragma unroll
    for (int c = 0; c < 2; c++) {
      bf16x8 af[4], bfr[4];
      const int kx = (c * 4 + lq) ^ l7;
#pragma unroll
      for (int t = 0; t < 4; t++) {
        af[t]  = *(const bf16x8*)(As + (((wm + t * 16 + lm) << 3) + kx) * 8);
        bfr[t] = *(const bf16x8*)(Bs + (((wn + t * 16 + lm) << 3) + kx) * 8);
      }
#pragma unroll
      for (int mt = 0; mt < 4; mt++)
#pragma unroll
        for (int nt = 0; nt < 4; nt++)
          acc[mt][nt] = __builtin_amdgcn_mfma_f32_16x16x32_bf16(
              af[mt], bfr[nt], acc[mt][nt], 0, 0, 0);
    }
    __syncthreads();
  }

  // save modulation (+ bias) packed bf16; reset acc
  unsigned int modp[4][4][2];
#pragma unroll
  for (int nt = 0; nt < 4; nt++) {
    int gc = n0 + wn + nt * 16 + lm;
    float bmod = 0.f;
    if (gc < 3 * DMODEL) {
      int sec = (gc >= 5400) ? 2 : ((gc >= 2700) ? 1 : 0);
      int d = gc - sec * DMODEL;
      const float* u1 = (sec == 0) ? b1q : ((sec == 1) ? b1k : b1v);
      const float* u2 = (sec == 0) ? b2q : ((sec == 1) ? b2k : b2v);
      bmod = u1[d] + u2[d];
    }
#pragma unroll
    for (int mt = 0; mt < 4; mt++) {
#pragma unroll
      for (int h = 0; h < 2; h++) {
        unsigned int lo = f2b(acc[mt][nt][2 * h] + bmod);
        unsigned int hi = f2b(acc[mt][nt][2 * h + 1] + bmod);
        modp[mt][nt][h] = lo | (hi << 16);
      }
    }
  }
#pragma unroll
  for (int i = 0; i < 4; i++)
#pragma unroll
    for (int j = 0; j < 4; j++) acc[i][j] = (f32x4){0.f, 0.f, 0.f, 0.f};

  // ---------------- phase B: main GEMM, K = 2752 ----------------
  for (int k0 = 0; k0 < KP1; k0 += 64) {
#pragma unroll
    for (int r = 0; r < 4; r++) {
      gl2lds16(Xb + (size_t)(m0 + prow[r]) * KP1 + pcl[r] + k0, As + ldsoff[r]);
      gl2lds16(Wt + (size_t)(n0 + prow[r]) * KP1 + pcl[r] + k0, Bs + ldsoff[r]);
    }
    __syncthreads();
#pragma unroll
    for (int c = 0; c < 2; c++) {
      bf16x8 af[4], bfr[4];
      const int kx = (c * 4 + lq) ^ l7;
#pragma unroll
      for (int t = 0; t < 4; t++) {
        af[t]  = *(const bf16x8*)(As + (((wm + t * 16 + lm) << 3) + kx) * 8);
        bfr[t] = *(const bf16x8*)(Bs + (((wn + t * 16 + lm) << 3) + kx) * 8);
      }
#pragma unroll
      for (int mt = 0; mt < 4; mt++)
#pragma unroll
        for (int nt = 0; nt < 4; nt++)
          acc[mt][nt] = __builtin_amdgcn_mfma_f32_16x16x32_bf16(
              af[mt], bfr[nt], acc[mt][nt], 0, 0, 0);
    }
    __syncthreads();
  }

  // ---------------- epilogue: qkv = (main + b) * mod ----------------
#pragma unroll
  for (int nt = 0; nt < 4; nt++) {
    int gc = n0 + wn + nt * 16 + lm;
    float bmv = 0.f;
    if (gc < 3 * DMODEL) {
      int sec = (gc >= 5400) ? 2 : ((gc >= 2700) ? 1 : 0);
      int d = gc - sec * DMODEL;
      const float* bm = (sec == 0) ? bq_ : ((sec == 1) ? bk_ : bv_);
      bmv = bm[d];
    }
#pragma unroll
    for (int mt = 0; mt < 4; mt++) {
      int grb = m0 + wm + mt * 16 + lq * 4;   // C/D: col=lane&15, row=quad*4+i
#pragma unroll
      for (int i = 0; i < 4; i++) {
        float mod = b2f((unsigned short)(modp[mt][nt][i >> 1] >> ((i & 1) * 16)));
        MQ[(size_t)(grb + i) * NCOLS + gc] = f2b((acc[mt][nt][i] + bmv) * mod);
      }
    }
  }
}

// ---------------------------------------------------------------------------
// Fused attention (9x9) + softmax + residual + LayerNorm (unchanged, verified)
// ---------------------------------------------------------------------------
__global__ __launch_bounds__(256, 2) void attn_ln(
    const unsigned short* __restrict__ qkv,  // [9216][8192] bf16 (q|k|v packed)
    const float* __restrict__ x,             // [9216][2700] fp32
    const float* __restrict__ gamma, const float* __restrict__ beta,
    float* __restrict__ out)                 // [9216][2700] fp32
{
  __shared__ float part[4][81];
  __shared__ float sc[81];
  __shared__ float redS[4][9], redQ[4][9];
  __shared__ float muL[9], rsL[9];

  const int b = blockIdx.x;
  const int tid = threadIdx.x, wave = tid >> 6, lane = tid & 63;
  const unsigned short* qb = qkv + (size_t)b * 9 * NCOLS;

  // ---- phase 1: scores S[i][j] = q_i . k_j via 16x16x32 MFMA, K-split ----
  {
    const int l15 = lane & 15, lq8 = (lane >> 4) * 8;
    const int rA = (l15 < 9) ? l15 : 8;                 // clamp: rows 9..15 junk
    const unsigned short* qrow = qb + (size_t)rA * NCOLS;          // 16B aligned
    const unsigned short* krow = qb + (size_t)rA * NCOLS + DMODEL; // 8B aligned
    f32x4 accS = (f32x4){0.f, 0.f, 0.f, 0.f};
    for (int s = wave; s < 85; s += 4) {                // 85 = ceil(2700/32)
      int k0 = s * 32 + lq8;
      union { uint2 u[2]; unsigned int w[4]; bf16x8 v; } au, bu;
      au.u[0] = *(const uint2*)(qrow + k0);
      au.u[1] = *(const uint2*)(qrow + k0 + 4);
      bu.u[0] = *(const uint2*)(krow + k0);
      bu.u[1] = *(const uint2*)(krow + k0 + 4);
      if (s == 84) {                                    // mask k >= 2700
#pragma unroll
        for (int wd = 0; wd < 4; wd++)
          if (k0 + 2 * wd >= DMODEL) { au.w[wd] = 0u; bu.w[wd] = 0u; }
      }
      accS = __builtin_amdgcn_mfma_f32_16x16x32_bf16(au.v, bu.v, accS, 0, 0, 0);
    }
#pragma unroll
    for (int i = 0; i < 4; i++) {
      int row = (lane >> 4) * 4 + i, col = l15;
      if (row < 9 && col < 9) part[wave][row * 9 + col] = accS[i];
    }
  }
  __syncthreads();

  if (tid < 81)
    sc[tid] = (part[0][tid] + part[1][tid] + part[2][tid] + part[3][tid])
              * 0.019245008972987526f;                  // 1/sqrt(2700)
  __syncthreads();

  // ---- phase 2: softmax per row (threads 0..8) ----
  if (tid < 9) {
    float mx = -1e30f;
#pragma unroll
    for (int j = 0; j < 9; j++) mx = fmaxf(mx, sc[tid * 9 + j]);
    float e[9], sum = 0.f;
#pragma unroll
    for (int j = 0; j < 9; j++) { e[j] = __expf(sc[tid * 9 + j] - mx); sum += e[j]; }
    float inv = 1.f / sum;
#pragma unroll
    for (int j = 0; j < 9; j++) sc[tid * 9 + j] = e[j] * inv;
  }
  __syncthreads();

  // ---- phase 3: t = x + A.V for all 9 rows, per float4 column-chunk ----
  float sum[9], sq[9];
#pragma unroll
  for (int i = 0; i < 9; i++) { sum[i] = 0.f; sq[i] = 0.f; }
  unsigned int pv[9][3][2];
#pragma unroll
  for (int c = 0; c < 3; c++) {
    int e = tid + c * 256;
    if (e < 675) {                                      // 675 = 2700/4
      float4 t4[9];
#pragma unroll
      for (int i = 0; i < 9; i++)
        t4[i] = ((const float4*)(x + (size_t)(b * 9 + i) * DMODEL))[e];
#pragma unroll
      for (int j = 0; j < 9; j++) {
        ushort4 vv = ((const ushort4*)(qb + (size_t)j * NCOLS + 5400))[e];
        float v0 = b2f(vv.x), v1 = b2f(vv.y), v2 = b2f(vv.z), v3 = b2f(vv.w);
#pragma unroll
        for (int i = 0; i < 9; i++) {
          float p = sc[i * 9 + j];
          t4[i].x += p * v0; t4[i].y += p * v1;
          t4[i].z += p * v2; t4[i].w += p * v3;
        }
      }
#pragma unroll
      for (int i = 0; i < 9; i++) {
        sum[i] += t4[i].x + t4[i].y + t4[i].z + t4[i].w;
        sq[i]  += t4[i].x * t4[i].x + t4[i].y * t4[i].y
                + t4[i].z * t4[i].z + t4[i].w * t4[i].w;
        pv[i][c][0] = (unsigned int)f2b(t4[i].x) | ((unsigned int)f2b(t4[i].y) << 16);
        pv[i][c][1] = (unsigned int)f2b(t4[i].z) | ((unsigned int)f2b(t4[i].w) << 16);
      }
    }
  }

  // ---- phase 4: block reduction for all 9 rows ----
#pragma unroll
  for (int i = 0; i < 9; i++) {
    float s = sum[i], q = sq[i];
#pragma unroll
    for (int off = 32; off > 0; off >>= 1) {
      s += __shfl_down(s, off, 64);
      q += __shfl_down(q, off, 64);
    }
    if (lane == 0) { redS[wave][i] = s; redQ[wave][i] = q; }
  }
  __syncthreads();
  if (tid < 9) {
    float ts = redS[0][tid] + redS[1][tid] + redS[2][tid] + redS[3][tid];
    float tq = redQ[0][tid] + redQ[1][tid] + redQ[2][tid] + redQ[3][tid];
    float mu = ts * (1.f / 2700.f);
    muL[tid] = mu;
    rsL[tid] = rsqrtf(tq * (1.f / 2700.f) - mu * mu + 1e-5f);
  }
  __syncthreads();

  // ---- phase 5: LN write, float4 ----
#pragma unroll
  for (int c = 0; c < 3; c++) {
    int e = tid + c * 256;
    if (e < 675) {
      float4 g = ((const float4*)gamma)[e];
      float4 bb = ((const float4*)beta)[e];
#pragma unroll
      for (int i = 0; i < 9; i++) {
        float m = muL[i], r = rsL[i];
        float t0 = b2f((unsigned short)(pv[i][c][0] & 0xFFFF));
        float t1 = b2f((unsigned short)(pv[i][c][0] >> 16));
        float t2 = b2f((unsigned short)(pv[i][c][1] & 0xFFFF));
        float t3 = b2f((unsigned short)(pv[i][c][1] >> 16));
        float4 o;
        o.x = (t0 - m) * r * g.x + bb.x;
        o.y = (t1 - m) * r * g.y + bb.y;
        o.z = (t2 - m) * r * g.z + bb.z;
        o.w = (t3 - m) * r * g.w + bb.w;
        ((float4*)(out + (size_t)(b * 9 + i) * DMODEL))[e] = o;
      }
    }
  }
}

// ---------------------------------------------------------------------------
extern "C" void kernel_launch(void* const* d_in, const int* in_sizes, int n_in,
                              void* d_out, int out_size, void* d_ws, size_t ws_size,
                              hipStream_t stream) {
  const float* state = (const float*)d_in[0];
  const float* H1    = (const float*)d_in[1];
  const float* H2    = (const float*)d_in[2];
  const float* Wq    = (const float*)d_in[3];
  const float* bq    = (const float*)d_in[4];
  const float* Wk    = (const float*)d_in[5];
  const float* bk    = (const float*)d_in[6];
  const float* Wv    = (const float*)d_in[7];
  const float* bv    = (const float*)d_in[8];
  const float* WC1q  = (const float*)d_in[9];
  const float* bC1q  = (const float*)d_in[10];
  const float* WC1k  = (const float*)d_in[11];
  const float* bC1k  = (const float*)d_in[12];
  const float* WC1v  = (const float*)d_in[13];
  const float* bC1v  = (const float*)d_in[14];
  const float* WC2q  = (const float*)d_in[15];
  const float* bC2q  = (const float*)d_in[16];
  const float* WC2k  = (const float*)d_in[17];
  const float* bC2k  = (const float*)d_in[18];
  const float* WC2v  = (const float*)d_in[19];
  const float* bC2v  = (const float*)d_in[20];
  const float* gamma = (const float*)d_in[21];
  const float* beta  = (const float*)d_in[22];
  float* out = (float*)d_out;

  // workspace layout (256B aligned), total 282,460,160 B
  char* ws = (char*)d_ws;
  unsigned short* Xb  = (unsigned short*)(ws + 0);            // 9216*2752*2
  unsigned short* Wt  = (unsigned short*)(ws + 50724864);     // 8192*2752*2
  unsigned short* Hb  = (unsigned short*)(ws + 95813632);     // 9216*1024*2
  unsigned short* WCt = (unsigned short*)(ws + 114688000);    // 8192*1024*2
  unsigned short* MQ  = (unsigned short*)(ws + 131465216);    // 9216*8192*2

  // 1) convert / pack (vectorized / full-line versions)
  cvt_x<<<dim3(12384), dim3(256), 0, stream>>>(state, Xb);
  cvt_wqkv<<<dim3(43, 128), dim3(256), 0, stream>>>(Wq, Wk, Wv, Wt);
  cvt_h<<<dim3(4608), dim3(256), 0, stream>>>(H1, H2, Hb);
  cvt_wc<<<dim3(16, 128), dim3(256), 0, stream>>>(WC1q, WC1k, WC1v,
                                                  WC2q, WC2k, WC2v, WCt);

  // 2) fused double GEMM: MQ = (Xb@Wt^T + b) * (Hb@WCt^T + bc)
  gemm_fused<<<dim3(NCOLS / 128, MROWS / 128), dim3(256), 0, stream>>>(
      Xb, Wt, Hb, WCt, MQ, bq, bk, bv, bC1q, bC1k, bC1v, bC2q, bC2k, bC2v);

  // 3) attention + softmax + residual + layernorm
  attn_ln<<<dim3(1024), dim3(256), 0, stream>>>(MQ, state, gamma, beta, out);
}